// Round 1
// 545.811 us; speedup vs baseline: 1.0847x; 1.0847x over previous
//
#include <hip/hip_runtime.h>
#include <math.h>

#define S_TOK 8192
#define DDIM 2048
#define HDIM 2048
#define NE 8
#define CAP 2048
#define NBATCH 4
#define TT 2048

typedef _Float16 f16;
typedef _Float16 f16x4 __attribute__((ext_vector_type(4)));
typedef _Float16 f16x8 __attribute__((ext_vector_type(8)));
typedef float f32x4 __attribute__((ext_vector_type(4)));

typedef __attribute__((address_space(1))) const void* gas_ptr;
typedef __attribute__((address_space(3))) void* las_ptr;

// ---------------- gating: logits = x @ wg (fp64 accum), top-2, renorm weights ----------------
// lane <-> d mapping: x reads 256B coalesced, wg reads 32B/lane contiguous (2KB/instr).
// also zero-inits slot_token and zacc (blocks 0..63) so no separate memsets are needed
__global__ __launch_bounds__(256) void gating_kernel(const float* __restrict__ x,
                                                     const float* __restrict__ wg,
                                                     int* __restrict__ eid,
                                                     float* __restrict__ wts,
                                                     int* __restrict__ slot_token,
                                                     float* __restrict__ zacc) {
  if (blockIdx.x < 64) {
    int i = blockIdx.x * 256 + threadIdx.x;
    slot_token[i] = 0;
    zacc[i] = 0.f;
  }
  int wid = threadIdx.x >> 6;
  int lane = threadIdx.x & 63;
  int s = blockIdx.x * 4 + wid;
  const float* xr = x + (size_t)s * DDIM;
  double acc[8];
#pragma unroll
  for (int e = 0; e < 8; ++e) acc[e] = 0.0;
  for (int d0 = 0; d0 < DDIM; d0 += 64) {
    float xs = xr[d0 + lane];
    const float4* wp = (const float4*)(wg + (size_t)(d0 + lane) * 8);
    float4 g0 = wp[0];
    float4 g1 = wp[1];
    double xd = (double)xs;
    acc[0] += xd * (double)g0.x; acc[1] += xd * (double)g0.y;
    acc[2] += xd * (double)g0.z; acc[3] += xd * (double)g0.w;
    acc[4] += xd * (double)g1.x; acc[5] += xd * (double)g1.y;
    acc[6] += xd * (double)g1.z; acc[7] += xd * (double)g1.w;
  }
#pragma unroll
  for (int e = 0; e < 8; ++e) {
    double v = acc[e];
    for (int off = 32; off > 0; off >>= 1) v += __shfl_down(v, off, 64);
    acc[e] = v;
  }
  if (lane == 0) {
    int e0 = 0; double l0 = acc[0];
    for (int e = 1; e < 8; ++e) if (acc[e] > l0) { l0 = acc[e]; e0 = e; }
    int e1 = -1; double l1 = -1e300;
    for (int e = 0; e < 8; ++e) if (e != e0 && acc[e] > l1) { l1 = acc[e]; e1 = e; }
    double pe = exp(l1 - l0);
    double inv = 1.0 / (1.0 + pe);
    eid[2 * s] = e0; eid[2 * s + 1] = e1;
    wts[2 * s] = (float)inv; wts[2 * s + 1] = (float)(pe * inv);
  }
}

// ---------------- capacity scan (deepspeed semantics): 4 waves, two-phase, 1 barrier ----------------
__global__ __launch_bounds__(256) void scan_kernel(const int* __restrict__ eid,
                                                   int* __restrict__ locb,
                                                   int* __restrict__ slot_token) {
  __shared__ int seg[4][2][8];
  __shared__ int base[4][2][8];
  int tid = threadIdx.x, wid = tid >> 6, lane = tid & 63;
  unsigned long long lower = (lane == 0) ? 0ull : ((~0ull) >> (64 - lane));
  const int2* eid2 = (const int2*)eid;
  int c0 = 0, c1 = 0;  // valid in lanes 0..7 (expert == lane)
  for (int r = 0; r < 32; ++r) {
    int2 ee = eid2[wid * 2048 + r * 64 + lane];
#pragma unroll
    for (int e = 0; e < 8; ++e) {
      unsigned long long b0 = __ballot(ee.x == e);
      unsigned long long b1 = __ballot(ee.y == e);
      if (lane == e) { c0 += __popcll(b0); c1 += __popcll(b1); }
    }
  }
  if (lane < 8) { seg[wid][0][lane] = c0; seg[wid][1][lane] = c1; }
  __syncthreads();
  if (lane < 8) {
    int e = lane;
    int tot0 = seg[0][0][e] + seg[1][0][e] + seg[2][0][e] + seg[3][0][e];
    int b0 = 0, b1 = tot0;
    for (int w = 0; w < wid; ++w) { b0 += seg[w][0][e]; b1 += seg[w][1][e]; }
    base[wid][0][e] = b0; base[wid][1][e] = b1;
  }
  // base[wid] written and read only by wave wid; DS ops are in-order per wave -> no barrier.
  for (int r = 0; r < 32; ++r) {
    int2 ee = eid2[wid * 2048 + r * 64 + lane];
    int rank0 = 0, rank1 = 0, add0 = 0, add1 = 0;
#pragma unroll
    for (int e = 0; e < 8; ++e) {
      unsigned long long b0 = __ballot(ee.x == e);
      unsigned long long b1 = __ballot(ee.y == e);
      if (ee.x == e) rank0 = __popcll(b0 & lower);
      if (ee.y == e) rank1 = __popcll(b1 & lower);
      if (lane == e) { add0 = __popcll(b0); add1 = __popcll(b1); }
    }
    int loc0 = base[wid][0][ee.x] + rank0;
    int loc1 = base[wid][1][ee.y] + rank1;
    int s = wid * 2048 + r * 64 + lane;
    int2 lo; lo.x = loc0; lo.y = loc1;
    *(int2*)&locb[2 * s] = lo;
    if (loc0 < CAP) slot_token[ee.x * CAP + loc0] = s;
    if (loc1 < CAP) slot_token[ee.y * CAP + loc1] = s;
    if (lane < 8) {
      atomicAdd(&base[wid][0][lane], add0);
      atomicAdd(&base[wid][1][lane], add1);
    }
  }
}

// ---------------- fused prep: w1 transpose->f16, w2 rowsum, b2 sum, A16 gather ----------------
#define W1T_BLOCKS 8192
#define W2S_BLOCKS 4096
#define ABUILD_BASE (W1T_BLOCKS + W2S_BLOCKS + 1)
__global__ __launch_bounds__(256) void prep_kernel(const float* __restrict__ w1,
                                                   const float* __restrict__ w2,
                                                   const float* __restrict__ b2,
                                                   const float* __restrict__ x,
                                                   const int* __restrict__ slot_token,
                                                   f16* __restrict__ W1T,
                                                   float* __restrict__ w2s,
                                                   float* __restrict__ b2s,
                                                   f16* __restrict__ A16) {
  __shared__ float tile[64 * 65];  // 16.6 KB, +1 padding -> conflict-free transpose
  int bid = blockIdx.x, tid = threadIdx.x;
  if (bid >= ABUILD_BASE) {
    // ---- abuild: gather token rows into f16 [E,C,D] ----
    int slot = bid - ABUILD_BASE;
    int s = slot_token[slot];
    const float4* x4 = (const float4*)x + (size_t)s * 512;
    f16x4* outp = (f16x4*)(A16 + (size_t)slot * DDIM);
#pragma unroll
    for (int i = 0; i < 2; ++i) {
      int v = i * 256 + tid;
      float4 xv = x4[v];
      f16x4 h;
      h[0] = (f16)xv.x; h[1] = (f16)xv.y; h[2] = (f16)xv.z; h[3] = (f16)xv.w;
      outp[v] = h;
    }
    return;
  }
  if (bid < W1T_BLOCKS) {
    // ---- w1t: [E,D,H] fp32 -> [E,H,D] f16 via padded fp32 LDS tile ----
    int e = bid >> 10, rem = bid & 1023;
    int d0 = (rem >> 5) << 6;
    int h0 = (rem & 31) << 6;
    const float* w1e = w1 + (size_t)e * DDIM * HDIM;
#pragma unroll
    for (int i = 0; i < 4; ++i) {
      int linear = i * 256 + tid;       // 1024 float4 slots = 64 rows x 16
      int r = linear >> 4, c4 = linear & 15;
      float4 v = *(const float4*)(w1e + (size_t)(d0 + r) * HDIM + h0 + c4 * 4);
      float* t = &tile[r * 65 + c4 * 4];
      t[0] = v.x; t[1] = v.y; t[2] = v.z; t[3] = v.w;
    }
    __syncthreads();
    f16* W1Te = W1T + (size_t)e * HDIM * DDIM;
#pragma unroll
    for (int i = 0; i < 2; ++i) {
      int linear = i * 256 + tid;       // 512 slots = 64 h-rows x 8 lanes
      int hr = linear >> 3, l8 = linear & 7;
      f16x8 o;
#pragma unroll
      for (int j = 0; j < 8; ++j) o[j] = (f16)tile[(l8 * 8 + j) * 65 + hr];
      *(f16x8*)(W1Te + (size_t)(h0 + hr) * DDIM + d0 + l8 * 8) = o;
    }
    return;
  }
  if (bid < W1T_BLOCKS + W2S_BLOCKS) {
    // ---- w2s[e,h] = sum_d w2[e,h,d], one row per wave ----
    int wid = tid >> 6, lane = tid & 63;
    int row = (bid - W1T_BLOCKS) * 4 + wid;
    const float4* w24 = (const float4*)w2;
    float acc = 0.f;
    for (int j = 0; j < 8; ++j) {
      float4 v = w24[(size_t)row * 512 + j * 64 + lane];
      acc += v.x + v.y + v.z + v.w;
    }
    for (int off = 32; off > 0; off >>= 1) acc += __shfl_down(acc, off, 64);
    if (lane == 0) w2s[row] = acc;
    return;
  }
  // ---- b2s: 8 experts, 32 lanes each ----
  {
    int e = tid >> 5, l32 = tid & 31;
    float acc = 0.f;
    for (int j = 0; j < 64; ++j) acc += b2[e * 2048 + j * 32 + l32];
    for (int off = 16; off > 0; off >>= 1) acc += __shfl_down(acc, off, 32);
    if (l32 == 0) b2s[e] = acc;
  }
}

// ---------------- GEMM1: 256x256 tile, BK=64, 8 waves, 8-phase pipelined schedule ----------------
// T3+T4+T2+T5 port of the 256sq 8-phase template (guide S5.5):
//  - LDS: 2 bufs x (A 256x64 + B 256x64) f16 = 128 KiB, double-buffered per K-tile.
//  - swizzled LDS content: within each 128B row, 16B slot c' holds logical chunk c'^(row&7)
//    -> ds_read_b128 fragment reads are <=2-way bank conflicts (free). global_load_lds keeps
//    the LDS destination linear; the SOURCE address is pre-swizzled per lane (rule #21).
//  - counted vmcnt(4) only at phases 4/8 (2 loads/half-tile, 2 half-tiles in flight).
//  - setprio(1) around each 16-MFMA cluster (T5; pays only on phase-split schedules).
//  - block mapping: expert = bid&7 -> one expert per XCD under round-robin dispatch (T1).

template <int MB, int NB>
__device__ __forceinline__ void quad_mfma(f32x4 (&acc)[8][4], const f16x8 (&av)[4][2],
                                          const f16x8 (&bv)[2][2]) {
#pragma unroll
  for (int mf = 0; mf < 4; ++mf)
#pragma unroll
    for (int nf = 0; nf < 2; ++nf) {
      f32x4 c = acc[MB + mf][NB + nf];
      c = __builtin_amdgcn_mfma_f32_16x16x32_f16(av[mf][0], bv[nf][0], c, 0, 0, 0);
      c = __builtin_amdgcn_mfma_f32_16x16x32_f16(av[mf][1], bv[nf][1], c, 0, 0, 0);
      acc[MB + mf][NB + nf] = c;
    }
}

__device__ __forceinline__ void lda4(f16x8 (&av)[4][2], const f16* p0, const f16* p1, int mh) {
#pragma unroll
  for (int mf = 0; mf < 4; ++mf) {
    av[mf][0] = *(const f16x8*)(p0 + (mh * 4 + mf) * 1024);
    av[mf][1] = *(const f16x8*)(p1 + (mh * 4 + mf) * 1024);
  }
}
__device__ __forceinline__ void ldb2(f16x8 (&bv)[2][2], const f16* p0, const f16* p1, int nh) {
#pragma unroll
  for (int nf = 0; nf < 2; ++nf) {
    bv[nf][0] = *(const f16x8*)(p0 + (nh * 2 + nf) * 1024);
    bv[nf][1] = *(const f16x8*)(p1 + (nh * 2 + nf) * 1024);
  }
}

// stage one 128-row half-tile (2 x global_load_lds_dwordx4 per thread-block wave set):
// call i covers rows h*128+i*64 .. +63; wave w owns 8 rows; lane l fetches row (l>>3),
// logical chunk (l&7)^(l>>3) so the linear LDS deposit realizes the XOR-swizzled layout.
__device__ __forceinline__ void stage_half(const f16* tile_rows, f16* lds_region,
                                           int T, int h, int wl8, int wu8, int cs) {
#pragma unroll
  for (int i = 0; i < 2; ++i) {
    const f16* g = tile_rows + (size_t)(h * 128 + i * 64 + wl8) * DDIM + T * 64 + cs * 8;
    f16* d = lds_region + (h * 128 + i * 64 + wu8) * 64;
    __builtin_amdgcn_global_load_lds((gas_ptr)g, (las_ptr)d, 16, 0, 0);
  }
}

__device__ __forceinline__ void bar() {
  asm volatile("" ::: "memory");
  __builtin_amdgcn_s_barrier();
  asm volatile("" ::: "memory");
}
__device__ __forceinline__ void mfma_open() {
  bar();
  asm volatile("s_waitcnt lgkmcnt(0)" ::: "memory");
  __builtin_amdgcn_sched_barrier(0);  // rule #18: keep MFMAs below the lgkmcnt
  __builtin_amdgcn_s_setprio(1);
}
__device__ __forceinline__ void mfma_close() {
  __builtin_amdgcn_s_setprio(0);
  bar();
}
__device__ __forceinline__ void mfma_close_w4() {
  __builtin_amdgcn_s_setprio(0);
  asm volatile("s_waitcnt vmcnt(4)" ::: "memory");  // counted: never 0 in main loop (T4)
  bar();
}
__device__ __forceinline__ void mfma_close_w0() {
  __builtin_amdgcn_s_setprio(0);
  asm volatile("s_waitcnt vmcnt(0)" ::: "memory");
  bar();
}

__global__ __launch_bounds__(512, 2) void gemm_kernel(const f16* __restrict__ A16,
                                                      const f16* __restrict__ W1T,
                                                      const float* __restrict__ b1,
                                                      const float* __restrict__ w2s,
                                                      float* __restrict__ zacc) {
  __shared__ __align__(16) f16 lds[4 * 256 * 64];  // 128 KiB
  const int tid = threadIdx.x;
  const int wid = tid >> 6, lane = tid & 63;
  const int wm = wid >> 2, wn = wid & 3;      // 2(M) x 4(N) wave grid, wave owns 128x64
  const int quad = lane >> 4, l15 = lane & 15;
  const int l3 = lane >> 3, c7 = lane & 7;
  const int cs = c7 ^ l3;                     // pre-swizzled source chunk
  const int wl8 = wid * 8 + l3, wu8 = wid * 8;

  int bid = blockIdx.x;
  int e = bid & 7;                            // one expert per XCD (round-robin dispatch)
  int idx = bid >> 3;                         // 0..63 within expert
  int cT = idx >> 3, hT = idx & 7;
  int c0 = cT * 256, h0 = hT * 256;

  const f16* Abase = A16 + ((size_t)e * CAP + c0) * DDIM;
  const f16* Bbase = W1T + ((size_t)e * HDIM + h0) * DDIM;

  f16* bufA0 = &lds[0];
  f16* bufB0 = &lds[16384];
  f16* bufA1 = &lds[2 * 16384];
  f16* bufB1 = &lds[3 * 16384];

  const int so0 = (quad ^ c7) * 8;            // swizzled slot, k-frag 0
  const int so1 = ((quad + 4) ^ c7) * 8;      // swizzled slot, k-frag 1
  const f16* a0k0 = bufA0 + (wm * 128 + l15) * 64 + so0;
  const f16* a0k1 = bufA0 + (wm * 128 + l15) * 64 + so1;
  const f16* a1k0 = a0k0 + 2 * 16384;
  const f16* a1k1 = a0k1 + 2 * 16384;
  const f16* b0k0 = bufB0 + (wn * 64 + l15) * 64 + so0;
  const f16* b0k1 = bufB0 + (wn * 64 + l15) * 64 + so1;
  const f16* b1k0 = b0k0 + 2 * 16384;
  const f16* b1k1 = b0k1 + 2 * 16384;

  f32x4 acc[8][4];
#pragma unroll
  for (int i = 0; i < 8; ++i)
#pragma unroll
    for (int jj = 0; jj < 4; ++jj) acc[i][jj] = (f32x4){0.f, 0.f, 0.f, 0.f};
  f16x8 fa[4][2], fb0[2][2], fb1[2][2];

  // prologue: tile0 A+B -> buf0 (8 loads), tile1 B -> buf1 (4 loads); wait oldest 8
  stage_half(Abase, bufA0, 0, 0, wl8, wu8, cs);
  stage_half(Abase, bufA0, 0, 1, wl8, wu8, cs);
  stage_half(Bbase, bufB0, 0, 0, wl8, wu8, cs);
  stage_half(Bbase, bufB0, 0, 1, wl8, wu8, cs);
  stage_half(Bbase, bufB1, 1, 0, wl8, wu8, cs);
  stage_half(Bbase, bufB1, 1, 1, wl8, wu8, cs);
  asm volatile("s_waitcnt vmcnt(4)" ::: "memory");
  bar();

#pragma unroll 1
  for (int it = 0; it < 15; ++it) {
    const int Ta = 2 * it + 1, Tb = 2 * it + 2, Tc = 2 * it + 3;
    // ---- K-tile 2*it (buf0): 4 phases ----
    lda4(fa, a0k0, a0k1, 0);                   // A m-frags 0-3 (12 ds_reads this phase)
    ldb2(fb0, b0k0, b0k1, 0);                  // B n-frags 0-1
    stage_half(Abase, bufA1, Ta, 0, wl8, wu8, cs);
    mfma_open(); quad_mfma<0, 0>(acc, fa, fb0); mfma_close();

    ldb2(fb1, b0k0, b0k1, 1);                  // B n-frags 2-3
    stage_half(Abase, bufA1, Ta, 1, wl8, wu8, cs);
    mfma_open(); quad_mfma<0, 2>(acc, fa, fb1); mfma_close();

    lda4(fa, a0k0, a0k1, 1);                   // A m-frags 4-7 (buf0 A fully read after this)
    stage_half(Bbase, bufB0, Tb, 0, wl8, wu8, cs);   // buf0 B free after phase 2
    mfma_open(); quad_mfma<4, 2>(acc, fa, fb1); mfma_close();

    stage_half(Bbase, bufB0, Tb, 1, wl8, wu8, cs);
    mfma_open(); quad_mfma<4, 0>(acc, fa, fb0); mfma_close_w4();  // tile Ta now resident

    // ---- K-tile 2*it+1 (buf1): 4 phases ----
    lda4(fa, a1k0, a1k1, 0);
    ldb2(fb0, b1k0, b1k1, 0);
    stage_half(Abase, bufA0, Tb, 0, wl8, wu8, cs);   // buf0 A free after phase 3
    mfma_open(); quad_mfma<0, 0>(acc, fa, fb0); mfma_close();

    ldb2(fb1, b1k0, b1k1, 1);
    stage_half(Abase, bufA0, Tb, 1, wl8, wu8, cs);
    mfma_open(); quad_mfma<0, 2>(acc, fa, fb1); mfma_close();

    lda4(fa, a1k0, a1k1, 1);
    stage_half(Bbase, bufB1, Tc, 0, wl8, wu8, cs);   // buf1 B free after phase 6
    mfma_open(); quad_mfma<4, 2>(acc, fa, fb1); mfma_close();

    stage_half(Bbase, bufB1, Tc, 1, wl8, wu8, cs);
    mfma_open(); quad_mfma<4, 0>(acc, fa, fb0); mfma_close_w4();  // tile Tb now resident
  }
  // peeled last iteration: tiles 30 (buf0), 31 (buf1); only tile31.Ah left to stage
  {
    lda4(fa, a0k0, a0k1, 0);
    ldb2(fb0, b0k0, b0k1, 0);
    stage_half(Abase, bufA1, 31, 0, wl8, wu8, cs);
    mfma_open(); quad_mfma<0, 0>(acc, fa, fb0); mfma_close();

    ldb2(fb1, b0k0, b0k1, 1);
    stage_half(Abase, bufA1, 31, 1, wl8, wu8, cs);
    mfma_open(); quad_mfma<0, 2>(acc, fa, fb1); mfma_close();

    lda4(fa, a0k0, a0k1, 1);
    mfma_open(); quad_mfma<4, 2>(acc, fa, fb1); mfma_close();

    mfma_open(); quad_mfma<4, 0>(acc, fa, fb0); mfma_close_w0();  // drain: tile31 resident

    lda4(fa, a1k0, a1k1, 0);
    ldb2(fb0, b1k0, b1k1, 0);
    mfma_open(); quad_mfma<0, 0>(acc, fa, fb0); mfma_close();

    ldb2(fb1, b1k0, b1k1, 1);
    mfma_open(); quad_mfma<0, 2>(acc, fa, fb1); mfma_close();

    lda4(fa, a1k0, a1k1, 1);
    mfma_open(); quad_mfma<4, 2>(acc, fa, fb1); mfma_close();

    mfma_open(); quad_mfma<4, 0>(acc, fa, fb0);
    __builtin_amdgcn_s_setprio(0);
  }

  // epilogue: rowsum over this block's 256 h-cols of relu(acc + b1) * w2s -> atomicAdd zacc
  float b1v[4], wsv[4];
#pragma unroll
  for (int nf = 0; nf < 4; ++nf) {
    int h = h0 + wn * 64 + nf * 16 + l15;
    b1v[nf] = b1[e * HDIM + h];
    wsv[nf] = w2s[e * HDIM + h];
  }
#pragma unroll
  for (int mf = 0; mf < 8; ++mf) {
    float pr[4];
#pragma unroll
    for (int rr = 0; rr < 4; ++rr) {
      float t = 0.f;
#pragma unroll
      for (int nf = 0; nf < 4; ++nf) {
        float v = acc[mf][nf][rr] + b1v[nf];
        t += (v > 0.f ? v : 0.f) * wsv[nf];
      }
      pr[rr] = t;
    }
#pragma unroll
    for (int rr = 0; rr < 4; ++rr)
#pragma unroll
      for (int off = 1; off < 16; off <<= 1) pr[rr] += __shfl_xor(pr[rr], off, 64);
    if (l15 == 0) {
      int m = c0 + wm * 128 + mf * 16 + quad * 4;
#pragma unroll
      for (int rr = 0; rr < 4; ++rr) atomicAdd(&zacc[e * CAP + m + rr], pr[rr]);
    }
  }
}

// ---------------- fused combine + per-batch-row log_softmax ----------------
__global__ __launch_bounds__(256) void tail_kernel(const int* __restrict__ eid,
                                                   const int* __restrict__ locb,
                                                   const float* __restrict__ wts,
                                                   const float* __restrict__ zacc,
                                                   const float* __restrict__ b2s,
                                                   float* __restrict__ out) {
  __shared__ float red[4];
  int b = blockIdx.x, tid = threadIdx.x;
  int wid = tid >> 6, lane = tid & 63;
  float v[8];
  float mx = -1e30f;
#pragma unroll
  for (int i = 0; i < 8; ++i) {
    int s = b * TT + i * 256 + tid;
    float zz = 0.f;
#pragma unroll
    for (int k = 0; k < 2; ++k) {
      int e = eid[2 * s + k], loc = locb[2 * s + k];
      if (loc < CAP) zz += wts[2 * s + k] * (zacc[e * CAP + loc] + b2s[e]);
    }
    v[i] = zz;
    mx = fmaxf(mx, zz);
  }
  for (int off = 32; off > 0; off >>= 1) mx = fmaxf(mx, __shfl_xor(mx, off, 64));
  if (lane == 0) red[wid] = mx;
  __syncthreads();
  mx = fmaxf(fmaxf(red[0], red[1]), fmaxf(red[2], red[3]));
  float sum = 0.f;
#pragma unroll
  for (int i = 0; i < 8; ++i) sum += expf(v[i] - mx);
  for (int off = 32; off > 0; off >>= 1) sum += __shfl_xor(sum, off, 64);
  __syncthreads();
  if (lane == 0) red[wid] = sum;
  __syncthreads();
  sum = red[0] + red[1] + red[2] + red[3];
  float lse = mx + logf(sum);
#pragma unroll
  for (int i = 0; i < 8; ++i) out[b * TT + i * 256 + tid] = v[i] - lse;
}

extern "C" void kernel_launch(void* const* d_in, const int* in_sizes, int n_in,
                              void* d_out, int out_size, void* d_ws, size_t ws_size,
                              hipStream_t stream) {
  const float* x  = (const float*)d_in[0];
  const float* wg = (const float*)d_in[1];
  const float* w1 = (const float*)d_in[2];
  const float* b1 = (const float*)d_in[3];
  const float* w2 = (const float*)d_in[4];
  const float* b2 = (const float*)d_in[5];
  float* out = (float*)d_out;

  char* ws = (char*)d_ws;
  size_t off = 0;
  auto alloc = [&](size_t bytes) -> char* {
    char* p = ws + off;
    off += (bytes + 255) & ~(size_t)255;
    return p;
  };
  f16* A16 = (f16*)alloc((size_t)NE * CAP * DDIM * 2);
  f16* W1T = (f16*)alloc((size_t)NE * HDIM * DDIM * 2);
  float* w2s = (float*)alloc((size_t)NE * HDIM * 4);
  float* b2s = (float*)alloc(NE * 4);
  int* eid = (int*)alloc((size_t)S_TOK * 2 * 4);
  float* wts = (float*)alloc((size_t)S_TOK * 2 * 4);
  int* locb = (int*)alloc((size_t)S_TOK * 2 * 4);
  int* slot_token = (int*)alloc((size_t)NE * CAP * 4);
  float* zacc = (float*)alloc((size_t)NE * CAP * 4);
  if (off > ws_size) return;  // workspace too small: fail loudly via wrong output

  gating_kernel<<<S_TOK / 4, 256, 0, stream>>>(x, wg, eid, wts, slot_token, zacc);
  scan_kernel<<<1, 256, 0, stream>>>(eid, locb, slot_token);
  prep_kernel<<<ABUILD_BASE + NE * CAP, 256, 0, stream>>>(w1, w2, b2, x, slot_token,
                                                          W1T, w2s, b2s, A16);
  gemm_kernel<<<NE * 64, 512, 0, stream>>>(A16, W1T, b1, w2s, zacc);
  tail_kernel<<<NBATCH, 256, 0, stream>>>(eid, locb, wts, zacc, b2s, out);
}

// Round 2
// 541.391 us; speedup vs baseline: 1.0935x; 1.0082x over previous
//
#include <hip/hip_runtime.h>
#include <math.h>

#define S_TOK 8192
#define DDIM 2048
#define HDIM 2048
#define NE 8
#define CAP 2048
#define NBATCH 4
#define TT 2048

typedef _Float16 f16;
typedef _Float16 f16x4 __attribute__((ext_vector_type(4)));
typedef _Float16 f16x8 __attribute__((ext_vector_type(8)));
typedef float f32x4 __attribute__((ext_vector_type(4)));

typedef __attribute__((address_space(1))) const void* gas_ptr;
typedef __attribute__((address_space(3))) void* las_ptr;

// ---------------- K1: fused independent prep ----------------
// blocks [0,8192): w1 transpose->f16 ; [8192,12288): w2 rowsum ; 12288: b2 sum ;
// [12289, 12289+2048): gating (+ zero-init of slot_token/zacc in first 64 gating blocks).
// Everything here depends only on raw inputs -> gating's memory traffic overlaps the
// weight transposes instead of serializing in front of them.
#define W1T_BLOCKS 8192
#define W2S_BLOCKS 4096
#define GATE_BASE (W1T_BLOCKS + W2S_BLOCKS + 1)
#define K1_GRID (GATE_BASE + S_TOK / 4)

__global__ __launch_bounds__(256) void prep_kernel(const float* __restrict__ w1,
                                                   const float* __restrict__ w2,
                                                   const float* __restrict__ b2,
                                                   const float* __restrict__ x,
                                                   const float* __restrict__ wg,
                                                   int* __restrict__ eid,
                                                   float* __restrict__ wts,
                                                   int* __restrict__ slot_token,
                                                   float* __restrict__ zacc,
                                                   f16* __restrict__ W1T,
                                                   float* __restrict__ w2s,
                                                   float* __restrict__ b2s) {
  __shared__ float tile[64 * 65];  // 16.6 KB, +1 padding -> conflict-free transpose
  int bid = blockIdx.x, tid = threadIdx.x;
  if (bid >= GATE_BASE) {
    // ---- gating: logits = x @ wg (fp64 accum), top-2, renorm weights ----
    int g = bid - GATE_BASE;
    if (g < 64) {
      int i = g * 256 + tid;
      slot_token[i] = 0;
      zacc[i] = 0.f;
    }
    int wid = tid >> 6;
    int lane = tid & 63;
    int s = g * 4 + wid;
    const float* xr = x + (size_t)s * DDIM;
    double acc[8];
#pragma unroll
    for (int e = 0; e < 8; ++e) acc[e] = 0.0;
    for (int d0 = 0; d0 < DDIM; d0 += 64) {
      float xs = xr[d0 + lane];
      const float4* wp = (const float4*)(wg + (size_t)(d0 + lane) * 8);
      float4 g0 = wp[0];
      float4 g1 = wp[1];
      double xd = (double)xs;
      acc[0] += xd * (double)g0.x; acc[1] += xd * (double)g0.y;
      acc[2] += xd * (double)g0.z; acc[3] += xd * (double)g0.w;
      acc[4] += xd * (double)g1.x; acc[5] += xd * (double)g1.y;
      acc[6] += xd * (double)g1.z; acc[7] += xd * (double)g1.w;
    }
#pragma unroll
    for (int e = 0; e < 8; ++e) {
      double v = acc[e];
      for (int off = 32; off > 0; off >>= 1) v += __shfl_down(v, off, 64);
      acc[e] = v;
    }
    if (lane == 0) {
      int e0 = 0; double l0 = acc[0];
      for (int e = 1; e < 8; ++e) if (acc[e] > l0) { l0 = acc[e]; e0 = e; }
      int e1 = -1; double l1 = -1e300;
      for (int e = 0; e < 8; ++e) if (e != e0 && acc[e] > l1) { l1 = acc[e]; e1 = e; }
      double pe = exp(l1 - l0);
      double inv = 1.0 / (1.0 + pe);
      eid[2 * s] = e0; eid[2 * s + 1] = e1;
      wts[2 * s] = (float)inv; wts[2 * s + 1] = (float)(pe * inv);
    }
    return;
  }
  if (bid < W1T_BLOCKS) {
    // ---- w1t: [E,D,H] fp32 -> [E,H,D] f16 via padded fp32 LDS tile ----
    int e = bid >> 10, rem = bid & 1023;
    int d0 = (rem >> 5) << 6;
    int h0 = (rem & 31) << 6;
    const float* w1e = w1 + (size_t)e * DDIM * HDIM;
#pragma unroll
    for (int i = 0; i < 4; ++i) {
      int linear = i * 256 + tid;       // 1024 float4 slots = 64 rows x 16
      int r = linear >> 4, c4 = linear & 15;
      float4 v = *(const float4*)(w1e + (size_t)(d0 + r) * HDIM + h0 + c4 * 4);
      float* t = &tile[r * 65 + c4 * 4];
      t[0] = v.x; t[1] = v.y; t[2] = v.z; t[3] = v.w;
    }
    __syncthreads();
    f16* W1Te = W1T + (size_t)e * HDIM * DDIM;
#pragma unroll
    for (int i = 0; i < 2; ++i) {
      int linear = i * 256 + tid;       // 512 slots = 64 h-rows x 8 lanes
      int hr = linear >> 3, l8 = linear & 7;
      f16x8 o;
#pragma unroll
      for (int j = 0; j < 8; ++j) o[j] = (f16)tile[(l8 * 8 + j) * 65 + hr];
      *(f16x8*)(W1Te + (size_t)(h0 + hr) * DDIM + d0 + l8 * 8) = o;
    }
    return;
  }
  if (bid < W1T_BLOCKS + W2S_BLOCKS) {
    // ---- w2s[e,h] = sum_d w2[e,h,d], one row per wave ----
    int wid = tid >> 6, lane = tid & 63;
    int row = (bid - W1T_BLOCKS) * 4 + wid;
    const float4* w24 = (const float4*)w2;
    float acc = 0.f;
    for (int j = 0; j < 8; ++j) {
      float4 v = w24[(size_t)row * 512 + j * 64 + lane];
      acc += v.x + v.y + v.z + v.w;
    }
    for (int off = 32; off > 0; off >>= 1) acc += __shfl_down(acc, off, 64);
    if (lane == 0) w2s[row] = acc;
    return;
  }
  // ---- b2s: 8 experts, 32 lanes each ----
  {
    int e = tid >> 5, l32 = tid & 31;
    float acc = 0.f;
    for (int j = 0; j < 64; ++j) acc += b2[e * 2048 + j * 32 + l32];
    for (int off = 16; off > 0; off >>= 1) acc += __shfl_down(acc, off, 32);
    if (l32 == 0) b2s[e] = acc;
  }
}

// ---------------- capacity scan (deepspeed semantics): 4 waves, two-phase, 1 barrier ----------------
__global__ __launch_bounds__(256) void scan_kernel(const int* __restrict__ eid,
                                                   int* __restrict__ locb,
                                                   int* __restrict__ slot_token) {
  __shared__ int seg[4][2][8];
  __shared__ int base[4][2][8];
  int tid = threadIdx.x, wid = tid >> 6, lane = tid & 63;
  unsigned long long lower = (lane == 0) ? 0ull : ((~0ull) >> (64 - lane));
  const int2* eid2 = (const int2*)eid;
  int c0 = 0, c1 = 0;  // valid in lanes 0..7 (expert == lane)
  for (int r = 0; r < 32; ++r) {
    int2 ee = eid2[wid * 2048 + r * 64 + lane];
#pragma unroll
    for (int e = 0; e < 8; ++e) {
      unsigned long long b0 = __ballot(ee.x == e);
      unsigned long long b1 = __ballot(ee.y == e);
      if (lane == e) { c0 += __popcll(b0); c1 += __popcll(b1); }
    }
  }
  if (lane < 8) { seg[wid][0][lane] = c0; seg[wid][1][lane] = c1; }
  __syncthreads();
  if (lane < 8) {
    int e = lane;
    int tot0 = seg[0][0][e] + seg[1][0][e] + seg[2][0][e] + seg[3][0][e];
    int b0 = 0, b1 = tot0;
    for (int w = 0; w < wid; ++w) { b0 += seg[w][0][e]; b1 += seg[w][1][e]; }
    base[wid][0][e] = b0; base[wid][1][e] = b1;
  }
  // base[wid] written and read only by wave wid; DS ops are in-order per wave -> no barrier.
  for (int r = 0; r < 32; ++r) {
    int2 ee = eid2[wid * 2048 + r * 64 + lane];
    int rank0 = 0, rank1 = 0, add0 = 0, add1 = 0;
#pragma unroll
    for (int e = 0; e < 8; ++e) {
      unsigned long long b0 = __ballot(ee.x == e);
      unsigned long long b1 = __ballot(ee.y == e);
      if (ee.x == e) rank0 = __popcll(b0 & lower);
      if (ee.y == e) rank1 = __popcll(b1 & lower);
      if (lane == e) { add0 = __popcll(b0); add1 = __popcll(b1); }
    }
    int loc0 = base[wid][0][ee.x] + rank0;
    int loc1 = base[wid][1][ee.y] + rank1;
    int s = wid * 2048 + r * 64 + lane;
    int2 lo; lo.x = loc0; lo.y = loc1;
    *(int2*)&locb[2 * s] = lo;
    if (loc0 < CAP) slot_token[ee.x * CAP + loc0] = s;
    if (loc1 < CAP) slot_token[ee.y * CAP + loc1] = s;
    if (lane < 8) {
      atomicAdd(&base[wid][0][lane], add0);
      atomicAdd(&base[wid][1][lane], add1);
    }
  }
}

// ---------------- abuild: gather token rows into f16 [E,C,D], one slot per wave ----------------
__global__ __launch_bounds__(256) void abuild_kernel(const float* __restrict__ x,
                                                     const int* __restrict__ slot_token,
                                                     f16* __restrict__ A16) {
  int wid = threadIdx.x >> 6, lane = threadIdx.x & 63;
  int slot = blockIdx.x * 4 + wid;
  int s = slot_token[slot];
  const float4* x4 = (const float4*)x + (size_t)s * 512 + lane;
  f16x4* outp = (f16x4*)(A16 + (size_t)slot * DDIM) + lane;
#pragma unroll
  for (int i = 0; i < 8; ++i) {
    float4 xv = x4[i * 64];
    f16x4 h;
    h[0] = (f16)xv.x; h[1] = (f16)xv.y; h[2] = (f16)xv.z; h[3] = (f16)xv.w;
    outp[i * 64] = h;
  }
}

// ---------------- GEMM1: 256x256 tile, BK=64, 8 waves, 8-phase pipelined schedule ----------------
// (unchanged from R1 -- verified at 147us / 0 bank conflicts; register-bound at 2 waves/SIMD)

template <int MB, int NB>
__device__ __forceinline__ void quad_mfma(f32x4 (&acc)[8][4], const f16x8 (&av)[4][2],
                                          const f16x8 (&bv)[2][2]) {
#pragma unroll
  for (int mf = 0; mf < 4; ++mf)
#pragma unroll
    for (int nf = 0; nf < 2; ++nf) {
      f32x4 c = acc[MB + mf][NB + nf];
      c = __builtin_amdgcn_mfma_f32_16x16x32_f16(av[mf][0], bv[nf][0], c, 0, 0, 0);
      c = __builtin_amdgcn_mfma_f32_16x16x32_f16(av[mf][1], bv[nf][1], c, 0, 0, 0);
      acc[MB + mf][NB + nf] = c;
    }
}

__device__ __forceinline__ void lda4(f16x8 (&av)[4][2], const f16* p0, const f16* p1, int mh) {
#pragma unroll
  for (int mf = 0; mf < 4; ++mf) {
    av[mf][0] = *(const f16x8*)(p0 + (mh * 4 + mf) * 1024);
    av[mf][1] = *(const f16x8*)(p1 + (mh * 4 + mf) * 1024);
  }
}
__device__ __forceinline__ void ldb2(f16x8 (&bv)[2][2], const f16* p0, const f16* p1, int nh) {
#pragma unroll
  for (int nf = 0; nf < 2; ++nf) {
    bv[nf][0] = *(const f16x8*)(p0 + (nh * 2 + nf) * 1024);
    bv[nf][1] = *(const f16x8*)(p1 + (nh * 2 + nf) * 1024);
  }
}

__device__ __forceinline__ void stage_half(const f16* tile_rows, f16* lds_region,
                                           int T, int h, int wl8, int wu8, int cs) {
#pragma unroll
  for (int i = 0; i < 2; ++i) {
    const f16* g = tile_rows + (size_t)(h * 128 + i * 64 + wl8) * DDIM + T * 64 + cs * 8;
    f16* d = lds_region + (h * 128 + i * 64 + wu8) * 64;
    __builtin_amdgcn_global_load_lds((gas_ptr)g, (las_ptr)d, 16, 0, 0);
  }
}

__device__ __forceinline__ void bar() {
  asm volatile("" ::: "memory");
  __builtin_amdgcn_s_barrier();
  asm volatile("" ::: "memory");
}
__device__ __forceinline__ void mfma_open() {
  bar();
  asm volatile("s_waitcnt lgkmcnt(0)" ::: "memory");
  __builtin_amdgcn_sched_barrier(0);  // rule #18: keep MFMAs below the lgkmcnt
  __builtin_amdgcn_s_setprio(1);
}
__device__ __forceinline__ void mfma_close() {
  __builtin_amdgcn_s_setprio(0);
  bar();
}
__device__ __forceinline__ void mfma_close_w4() {
  __builtin_amdgcn_s_setprio(0);
  asm volatile("s_waitcnt vmcnt(4)" ::: "memory");  // counted: never 0 in main loop (T4)
  bar();
}
__device__ __forceinline__ void mfma_close_w0() {
  __builtin_amdgcn_s_setprio(0);
  asm volatile("s_waitcnt vmcnt(0)" ::: "memory");
  bar();
}

__global__ __launch_bounds__(512, 2) void gemm_kernel(const f16* __restrict__ A16,
                                                      const f16* __restrict__ W1T,
                                                      const float* __restrict__ b1,
                                                      const float* __restrict__ w2s,
                                                      float* __restrict__ zacc) {
  __shared__ __align__(16) f16 lds[4 * 256 * 64];  // 128 KiB
  const int tid = threadIdx.x;
  const int wid = tid >> 6, lane = tid & 63;
  const int wm = wid >> 2, wn = wid & 3;      // 2(M) x 4(N) wave grid, wave owns 128x64
  const int quad = lane >> 4, l15 = lane & 15;
  const int l3 = lane >> 3, c7 = lane & 7;
  const int cs = c7 ^ l3;                     // pre-swizzled source chunk
  const int wl8 = wid * 8 + l3, wu8 = wid * 8;

  int bid = blockIdx.x;
  int e = bid & 7;                            // one expert per XCD (round-robin dispatch)
  int idx = bid >> 3;                         // 0..63 within expert
  int cT = idx >> 3, hT = idx & 7;
  int c0 = cT * 256, h0 = hT * 256;

  const f16* Abase = A16 + ((size_t)e * CAP + c0) * DDIM;
  const f16* Bbase = W1T + ((size_t)e * HDIM + h0) * DDIM;

  f16* bufA0 = &lds[0];
  f16* bufB0 = &lds[16384];
  f16* bufA1 = &lds[2 * 16384];
  f16* bufB1 = &lds[3 * 16384];

  const int so0 = (quad ^ c7) * 8;            // swizzled slot, k-frag 0
  const int so1 = ((quad + 4) ^ c7) * 8;      // swizzled slot, k-frag 1
  const f16* a0k0 = bufA0 + (wm * 128 + l15) * 64 + so0;
  const f16* a0k1 = bufA0 + (wm * 128 + l15) * 64 + so1;
  const f16* a1k0 = a0k0 + 2 * 16384;
  const f16* a1k1 = a0k1 + 2 * 16384;
  const f16* b0k0 = bufB0 + (wn * 64 + l15) * 64 + so0;
  const f16* b0k1 = bufB0 + (wn * 64 + l15) * 64 + so1;
  const f16* b1k0 = b0k0 + 2 * 16384;
  const f16* b1k1 = b0k1 + 2 * 16384;

  f32x4 acc[8][4];
#pragma unroll
  for (int i = 0; i < 8; ++i)
#pragma unroll
    for (int jj = 0; jj < 4; ++jj) acc[i][jj] = (f32x4){0.f, 0.f, 0.f, 0.f};
  f16x8 fa[4][2], fb0[2][2], fb1[2][2];

  // prologue: tile0 A+B -> buf0 (8 loads), tile1 B -> buf1 (4 loads); wait oldest 8
  stage_half(Abase, bufA0, 0, 0, wl8, wu8, cs);
  stage_half(Abase, bufA0, 0, 1, wl8, wu8, cs);
  stage_half(Bbase, bufB0, 0, 0, wl8, wu8, cs);
  stage_half(Bbase, bufB0, 0, 1, wl8, wu8, cs);
  stage_half(Bbase, bufB1, 1, 0, wl8, wu8, cs);
  stage_half(Bbase, bufB1, 1, 1, wl8, wu8, cs);
  asm volatile("s_waitcnt vmcnt(4)" ::: "memory");
  bar();

#pragma unroll 1
  for (int it = 0; it < 15; ++it) {
    const int Ta = 2 * it + 1, Tb = 2 * it + 2, Tc = 2 * it + 3;
    // ---- K-tile 2*it (buf0): 4 phases ----
    lda4(fa, a0k0, a0k1, 0);                   // A m-frags 0-3 (12 ds_reads this phase)
    ldb2(fb0, b0k0, b0k1, 0);                  // B n-frags 0-1
    stage_half(Abase, bufA1, Ta, 0, wl8, wu8, cs);
    mfma_open(); quad_mfma<0, 0>(acc, fa, fb0); mfma_close();

    ldb2(fb1, b0k0, b0k1, 1);                  // B n-frags 2-3
    stage_half(Abase, bufA1, Ta, 1, wl8, wu8, cs);
    mfma_open(); quad_mfma<0, 2>(acc, fa, fb1); mfma_close();

    lda4(fa, a0k0, a0k1, 1);                   // A m-frags 4-7 (buf0 A fully read after this)
    stage_half(Bbase, bufB0, Tb, 0, wl8, wu8, cs);   // buf0 B free after phase 2
    mfma_open(); quad_mfma<4, 2>(acc, fa, fb1); mfma_close();

    stage_half(Bbase, bufB0, Tb, 1, wl8, wu8, cs);
    mfma_open(); quad_mfma<4, 0>(acc, fa, fb0); mfma_close_w4();  // tile Ta now resident

    // ---- K-tile 2*it+1 (buf1): 4 phases ----
    lda4(fa, a1k0, a1k1, 0);
    ldb2(fb0, b1k0, b1k1, 0);
    stage_half(Abase, bufA0, Tb, 0, wl8, wu8, cs);   // buf0 A free after phase 3
    mfma_open(); quad_mfma<0, 0>(acc, fa, fb0); mfma_close();

    ldb2(fb1, b1k0, b1k1, 1);
    stage_half(Abase, bufA0, Tb, 1, wl8, wu8, cs);
    mfma_open(); quad_mfma<0, 2>(acc, fa, fb1); mfma_close();

    lda4(fa, a1k0, a1k1, 1);
    stage_half(Bbase, bufB1, Tc, 0, wl8, wu8, cs);   // buf1 B free after phase 6
    mfma_open(); quad_mfma<4, 2>(acc, fa, fb1); mfma_close();

    stage_half(Bbase, bufB1, Tc, 1, wl8, wu8, cs);
    mfma_open(); quad_mfma<4, 0>(acc, fa, fb0); mfma_close_w4();  // tile Tb now resident
  }
  // peeled last iteration: tiles 30 (buf0), 31 (buf1); only tile31.Ah left to stage
  {
    lda4(fa, a0k0, a0k1, 0);
    ldb2(fb0, b0k0, b0k1, 0);
    stage_half(Abase, bufA1, 31, 0, wl8, wu8, cs);
    mfma_open(); quad_mfma<0, 0>(acc, fa, fb0); mfma_close();

    ldb2(fb1, b0k0, b0k1, 1);
    stage_half(Abase, bufA1, 31, 1, wl8, wu8, cs);
    mfma_open(); quad_mfma<0, 2>(acc, fa, fb1); mfma_close();

    lda4(fa, a0k0, a0k1, 1);
    mfma_open(); quad_mfma<4, 2>(acc, fa, fb1); mfma_close();

    mfma_open(); quad_mfma<4, 0>(acc, fa, fb0); mfma_close_w0();  // drain: tile31 resident

    lda4(fa, a1k0, a1k1, 0);
    ldb2(fb0, b1k0, b1k1, 0);
    mfma_open(); quad_mfma<0, 0>(acc, fa, fb0); mfma_close();

    ldb2(fb1, b1k0, b1k1, 1);
    mfma_open(); quad_mfma<0, 2>(acc, fa, fb1); mfma_close();

    lda4(fa, a1k0, a1k1, 1);
    mfma_open(); quad_mfma<4, 2>(acc, fa, fb1); mfma_close();

    mfma_open(); quad_mfma<4, 0>(acc, fa, fb0);
    __builtin_amdgcn_s_setprio(0);
  }

  // epilogue: rowsum over this block's 256 h-cols of relu(acc + b1) * w2s -> atomicAdd zacc
  float b1v[4], wsv[4];
#pragma unroll
  for (int nf = 0; nf < 4; ++nf) {
    int h = h0 + wn * 64 + nf * 16 + l15;
    b1v[nf] = b1[e * HDIM + h];
    wsv[nf] = w2s[e * HDIM + h];
  }
#pragma unroll
  for (int mf = 0; mf < 8; ++mf) {
    float pr[4];
#pragma unroll
    for (int rr = 0; rr < 4; ++rr) {
      float t = 0.f;
#pragma unroll
      for (int nf = 0; nf < 4; ++nf) {
        float v = acc[mf][nf][rr] + b1v[nf];
        t += (v > 0.f ? v : 0.f) * wsv[nf];
      }
      pr[rr] = t;
    }
#pragma unroll
    for (int rr = 0; rr < 4; ++rr)
#pragma unroll
      for (int off = 1; off < 16; off <<= 1) pr[rr] += __shfl_xor(pr[rr], off, 64);
    if (l15 == 0) {
      int m = c0 + wm * 128 + mf * 16 + quad * 4;
#pragma unroll
      for (int rr = 0; rr < 4; ++rr) atomicAdd(&zacc[e * CAP + m + rr], pr[rr]);
    }
  }
}

// ---------------- fused combine + per-batch-row log_softmax (1024 thr: more gather TLP) ----------------
__global__ __launch_bounds__(1024) void tail_kernel(const int* __restrict__ eid,
                                                    const int* __restrict__ locb,
                                                    const float* __restrict__ wts,
                                                    const float* __restrict__ zacc,
                                                    const float* __restrict__ b2s,
                                                    float* __restrict__ out) {
  __shared__ float red[16];
  int b = blockIdx.x, tid = threadIdx.x;
  int wid = tid >> 6, lane = tid & 63;
  float v[2];
  float mx = -1e30f;
#pragma unroll
  for (int i = 0; i < 2; ++i) {
    int s = b * TT + i * 1024 + tid;
    float zz = 0.f;
#pragma unroll
    for (int k = 0; k < 2; ++k) {
      int e = eid[2 * s + k], loc = locb[2 * s + k];
      if (loc < CAP) zz += wts[2 * s + k] * (zacc[e * CAP + loc] + b2s[e]);
    }
    v[i] = zz;
    mx = fmaxf(mx, zz);
  }
  for (int off = 32; off > 0; off >>= 1) mx = fmaxf(mx, __shfl_xor(mx, off, 64));
  if (lane == 0) red[wid] = mx;
  __syncthreads();
  mx = red[0];
#pragma unroll
  for (int j = 1; j < 16; ++j) mx = fmaxf(mx, red[j]);
  float sum = expf(v[0] - mx) + expf(v[1] - mx);
  for (int off = 32; off > 0; off >>= 1) sum += __shfl_xor(sum, off, 64);
  __syncthreads();
  if (lane == 0) red[wid] = sum;
  __syncthreads();
  sum = 0.f;
#pragma unroll
  for (int j = 0; j < 16; ++j) sum += red[j];
  float lse = mx + logf(sum);
#pragma unroll
  for (int i = 0; i < 2; ++i) out[b * TT + i * 1024 + tid] = v[i] - lse;
}

extern "C" void kernel_launch(void* const* d_in, const int* in_sizes, int n_in,
                              void* d_out, int out_size, void* d_ws, size_t ws_size,
                              hipStream_t stream) {
  const float* x  = (const float*)d_in[0];
  const float* wg = (const float*)d_in[1];
  const float* w1 = (const float*)d_in[2];
  const float* b1 = (const float*)d_in[3];
  const float* w2 = (const float*)d_in[4];
  const float* b2 = (const float*)d_in[5];
  float* out = (float*)d_out;

  char* ws = (char*)d_ws;
  size_t off = 0;
  auto alloc = [&](size_t bytes) -> char* {
    char* p = ws + off;
    off += (bytes + 255) & ~(size_t)255;
    return p;
  };
  f16* A16 = (f16*)alloc((size_t)NE * CAP * DDIM * 2);
  f16* W1T = (f16*)alloc((size_t)NE * HDIM * DDIM * 2);
  float* w2s = (float*)alloc((size_t)NE * HDIM * 4);
  float* b2s = (float*)alloc(NE * 4);
  int* eid = (int*)alloc((size_t)S_TOK * 2 * 4);
  float* wts = (float*)alloc((size_t)S_TOK * 2 * 4);
  int* locb = (int*)alloc((size_t)S_TOK * 2 * 4);
  int* slot_token = (int*)alloc((size_t)NE * CAP * 4);
  float* zacc = (float*)alloc((size_t)NE * CAP * 4);
  if (off > ws_size) return;  // workspace too small: fail loudly via wrong output

  prep_kernel<<<K1_GRID, 256, 0, stream>>>(w1, w2, b2, x, wg, eid, wts, slot_token, zacc,
                                           W1T, w2s, b2s);
  scan_kernel<<<1, 256, 0, stream>>>(eid, locb, slot_token);
  abuild_kernel<<<NE * CAP / 4, 256, 0, stream>>>(x, slot_token, A16);
  gemm_kernel<<<NE * 64, 512, 0, stream>>>(A16, W1T, b1, w2s, zacc);
  tail_kernel<<<NBATCH, 1024, 0, stream>>>(eid, locb, wts, zacc, b2s, out);
}

// Round 3
// 527.164 us; speedup vs baseline: 1.1230x; 1.0270x over previous
//
#include <hip/hip_runtime.h>
#include <math.h>

#define S_TOK 8192
#define DDIM 2048
#define HDIM 2048
#define NE 8
#define CAP 2048
#define NBATCH 4
#define TT 2048

typedef _Float16 f16;
typedef _Float16 f16x4 __attribute__((ext_vector_type(4)));
typedef _Float16 f16x8 __attribute__((ext_vector_type(8)));
typedef float f32x4 __attribute__((ext_vector_type(4)));

typedef __attribute__((address_space(1))) const void* gas_ptr;
typedef __attribute__((address_space(3))) void* las_ptr;

// ---------------- K1: fused independent prep ----------------
// blocks [0,8192): w1 transpose->f16 ; [8192,12288): w2 rowsum ; 12288: b2 sum ;
// [12289, 12289+2048): gating (+ zero-init of slot_token/zacc in first 64 gating blocks).
#define W1T_BLOCKS 8192
#define W2S_BLOCKS 4096
#define GATE_BASE (W1T_BLOCKS + W2S_BLOCKS + 1)
#define K1_GRID (GATE_BASE + S_TOK / 4)

__global__ __launch_bounds__(256) void prep_kernel(const float* __restrict__ w1,
                                                   const float* __restrict__ w2,
                                                   const float* __restrict__ b2,
                                                   const float* __restrict__ x,
                                                   const float* __restrict__ wg,
                                                   int* __restrict__ eid,
                                                   float* __restrict__ wts,
                                                   int* __restrict__ slot_token,
                                                   float* __restrict__ zacc,
                                                   f16* __restrict__ W1T,
                                                   float* __restrict__ w2s,
                                                   float* __restrict__ b2s) {
  __shared__ float tile[64 * 65];  // 16.6 KB, +1 padding -> conflict-free transpose
  int bid = blockIdx.x, tid = threadIdx.x;
  if (bid >= GATE_BASE) {
    // ---- gating: logits = x @ wg (fp64 accum), top-2, renorm weights ----
    int g = bid - GATE_BASE;
    if (g < 64) {
      int i = g * 256 + tid;
      slot_token[i] = 0;
      zacc[i] = 0.f;
    }
    int wid = tid >> 6;
    int lane = tid & 63;
    int s = g * 4 + wid;
    const float* xr = x + (size_t)s * DDIM;
    double acc[8];
#pragma unroll
    for (int e = 0; e < 8; ++e) acc[e] = 0.0;
    for (int d0 = 0; d0 < DDIM; d0 += 64) {
      float xs = xr[d0 + lane];
      const float4* wp = (const float4*)(wg + (size_t)(d0 + lane) * 8);
      float4 g0 = wp[0];
      float4 g1 = wp[1];
      double xd = (double)xs;
      acc[0] += xd * (double)g0.x; acc[1] += xd * (double)g0.y;
      acc[2] += xd * (double)g0.z; acc[3] += xd * (double)g0.w;
      acc[4] += xd * (double)g1.x; acc[5] += xd * (double)g1.y;
      acc[6] += xd * (double)g1.z; acc[7] += xd * (double)g1.w;
    }
#pragma unroll
    for (int e = 0; e < 8; ++e) {
      double v = acc[e];
      for (int off = 32; off > 0; off >>= 1) v += __shfl_down(v, off, 64);
      acc[e] = v;
    }
    if (lane == 0) {
      int e0 = 0; double l0 = acc[0];
      for (int e = 1; e < 8; ++e) if (acc[e] > l0) { l0 = acc[e]; e0 = e; }
      int e1 = -1; double l1 = -1e300;
      for (int e = 0; e < 8; ++e) if (e != e0 && acc[e] > l1) { l1 = acc[e]; e1 = e; }
      double pe = exp(l1 - l0);
      double inv = 1.0 / (1.0 + pe);
      eid[2 * s] = e0; eid[2 * s + 1] = e1;
      wts[2 * s] = (float)inv; wts[2 * s + 1] = (float)(pe * inv);
    }
    return;
  }
  if (bid < W1T_BLOCKS) {
    // ---- w1t: [E,D,H] fp32 -> [E,H,D] f16 via padded fp32 LDS tile ----
    int e = bid >> 10, rem = bid & 1023;
    int d0 = (rem >> 5) << 6;
    int h0 = (rem & 31) << 6;
    const float* w1e = w1 + (size_t)e * DDIM * HDIM;
#pragma unroll
    for (int i = 0; i < 4; ++i) {
      int linear = i * 256 + tid;       // 1024 float4 slots = 64 rows x 16
      int r = linear >> 4, c4 = linear & 15;
      float4 v = *(const float4*)(w1e + (size_t)(d0 + r) * HDIM + h0 + c4 * 4);
      float* t = &tile[r * 65 + c4 * 4];
      t[0] = v.x; t[1] = v.y; t[2] = v.z; t[3] = v.w;
    }
    __syncthreads();
    f16* W1Te = W1T + (size_t)e * HDIM * DDIM;
#pragma unroll
    for (int i = 0; i < 2; ++i) {
      int linear = i * 256 + tid;       // 512 slots = 64 h-rows x 8 lanes
      int hr = linear >> 3, l8 = linear & 7;
      f16x8 o;
#pragma unroll
      for (int j = 0; j < 8; ++j) o[j] = (f16)tile[(l8 * 8 + j) * 65 + hr];
      *(f16x8*)(W1Te + (size_t)(h0 + hr) * DDIM + d0 + l8 * 8) = o;
    }
    return;
  }
  if (bid < W1T_BLOCKS + W2S_BLOCKS) {
    // ---- w2s[e,h] = sum_d w2[e,h,d], one row per wave ----
    int wid = tid >> 6, lane = tid & 63;
    int row = (bid - W1T_BLOCKS) * 4 + wid;
    const float4* w24 = (const float4*)w2;
    float acc = 0.f;
    for (int j = 0; j < 8; ++j) {
      float4 v = w24[(size_t)row * 512 + j * 64 + lane];
      acc += v.x + v.y + v.z + v.w;
    }
    for (int off = 32; off > 0; off >>= 1) acc += __shfl_down(acc, off, 64);
    if (lane == 0) w2s[row] = acc;
    return;
  }
  // ---- b2s: 8 experts, 32 lanes each ----
  {
    int e = tid >> 5, l32 = tid & 31;
    float acc = 0.f;
    for (int j = 0; j < 64; ++j) acc += b2[e * 2048 + j * 32 + l32];
    for (int off = 16; off > 0; off >>= 1) acc += __shfl_down(acc, off, 32);
    if (l32 == 0) b2s[e] = acc;
  }
}

// ---------------- capacity scan (deepspeed semantics): 16 waves, two-phase ----------------
// wave w owns tokens [w*512,(w+1)*512). Same ordering semantics as 4-wave version,
// 4x fewer serial ballot iterations.
__global__ __launch_bounds__(1024) void scan_kernel(const int* __restrict__ eid,
                                                    int* __restrict__ locb,
                                                    int* __restrict__ slot_token) {
  __shared__ int seg[16][2][8];
  __shared__ int base[16][2][8];
  int tid = threadIdx.x, wid = tid >> 6, lane = tid & 63;
  unsigned long long lower = (lane == 0) ? 0ull : ((~0ull) >> (64 - lane));
  const int2* eid2 = (const int2*)eid;
  int c0 = 0, c1 = 0;  // valid in lanes 0..7 (expert == lane)
  for (int r = 0; r < 8; ++r) {
    int2 ee = eid2[wid * 512 + r * 64 + lane];
#pragma unroll
    for (int e = 0; e < 8; ++e) {
      unsigned long long b0 = __ballot(ee.x == e);
      unsigned long long b1 = __ballot(ee.y == e);
      if (lane == e) { c0 += __popcll(b0); c1 += __popcll(b1); }
    }
  }
  if (lane < 8) { seg[wid][0][lane] = c0; seg[wid][1][lane] = c1; }
  __syncthreads();
  if (lane < 8) {
    int e = lane;
    int tot0 = 0;
#pragma unroll
    for (int w = 0; w < 16; ++w) tot0 += seg[w][0][e];
    int b0 = 0, b1 = tot0;
    for (int w = 0; w < wid; ++w) { b0 += seg[w][0][e]; b1 += seg[w][1][e]; }
    base[wid][0][e] = b0; base[wid][1][e] = b1;
  }
  // base[wid] written and read only by wave wid; DS ops are in-order per wave -> no barrier.
  for (int r = 0; r < 8; ++r) {
    int2 ee = eid2[wid * 512 + r * 64 + lane];
    int rank0 = 0, rank1 = 0, add0 = 0, add1 = 0;
#pragma unroll
    for (int e = 0; e < 8; ++e) {
      unsigned long long b0 = __ballot(ee.x == e);
      unsigned long long b1 = __ballot(ee.y == e);
      if (ee.x == e) rank0 = __popcll(b0 & lower);
      if (ee.y == e) rank1 = __popcll(b1 & lower);
      if (lane == e) { add0 = __popcll(b0); add1 = __popcll(b1); }
    }
    int loc0 = base[wid][0][ee.x] + rank0;
    int loc1 = base[wid][1][ee.y] + rank1;
    int s = wid * 512 + r * 64 + lane;
    int2 lo; lo.x = loc0; lo.y = loc1;
    *(int2*)&locb[2 * s] = lo;
    if (loc0 < CAP) slot_token[ee.x * CAP + loc0] = s;
    if (loc1 < CAP) slot_token[ee.y * CAP + loc1] = s;
    if (lane < 8) {
      atomicAdd(&base[wid][0][lane], add0);
      atomicAdd(&base[wid][1][lane], add1);
    }
  }
}

// ---------------- abuild: gather token rows into f16 [E,C,D], one slot per wave ----------------
__global__ __launch_bounds__(256) void abuild_kernel(const float* __restrict__ x,
                                                     const int* __restrict__ slot_token,
                                                     f16* __restrict__ A16) {
  int wid = threadIdx.x >> 6, lane = threadIdx.x & 63;
  int slot = blockIdx.x * 4 + wid;
  int s = slot_token[slot];
  const float4* x4 = (const float4*)x + (size_t)s * 512 + lane;
  f16x4* outp = (f16x4*)(A16 + (size_t)slot * DDIM) + lane;
#pragma unroll
  for (int i = 0; i < 8; ++i) {
    float4 xv = x4[i * 64];
    f16x4 h;
    h[0] = (f16)xv.x; h[1] = (f16)xv.y; h[2] = (f16)xv.z; h[3] = (f16)xv.w;
    outp[i * 64] = h;
  }
}

// ---------------- GEMM1: persistent 256-block, two 256x256 tiles per block, ----------------
// 8-wave 8-phase pipelined schedule kept WARM across the tile switch (no mid-kernel drain).
// Block handles (e, cT, hT) and (e, cT, hT+4): same A panel (L2-hot re-read), new B panel.

template <int MB, int NB>
__device__ __forceinline__ void quad_mfma(f32x4 (&acc)[8][4], const f16x8 (&av)[4][2],
                                          const f16x8 (&bv)[2][2]) {
#pragma unroll
  for (int mf = 0; mf < 4; ++mf)
#pragma unroll
    for (int nf = 0; nf < 2; ++nf) {
      f32x4 c = acc[MB + mf][NB + nf];
      c = __builtin_amdgcn_mfma_f32_16x16x32_f16(av[mf][0], bv[nf][0], c, 0, 0, 0);
      c = __builtin_amdgcn_mfma_f32_16x16x32_f16(av[mf][1], bv[nf][1], c, 0, 0, 0);
      acc[MB + mf][NB + nf] = c;
    }
}

__device__ __forceinline__ void lda4(f16x8 (&av)[4][2], const f16* p0, const f16* p1, int mh) {
#pragma unroll
  for (int mf = 0; mf < 4; ++mf) {
    av[mf][0] = *(const f16x8*)(p0 + (mh * 4 + mf) * 1024);
    av[mf][1] = *(const f16x8*)(p1 + (mh * 4 + mf) * 1024);
  }
}
__device__ __forceinline__ void ldb2(f16x8 (&bv)[2][2], const f16* p0, const f16* p1, int nh) {
#pragma unroll
  for (int nf = 0; nf < 2; ++nf) {
    bv[nf][0] = *(const f16x8*)(p0 + (nh * 2 + nf) * 1024);
    bv[nf][1] = *(const f16x8*)(p1 + (nh * 2 + nf) * 1024);
  }
}

// stage one 128-row half-tile; LDS dest linear, global source pre-swizzled (rule #21)
__device__ __forceinline__ void stage_half(const f16* tile_rows, f16* lds_region,
                                           int T, int h, int wl8, int wu8, int cs) {
#pragma unroll
  for (int i = 0; i < 2; ++i) {
    const f16* g = tile_rows + (size_t)(h * 128 + i * 64 + wl8) * DDIM + T * 64 + cs * 8;
    f16* d = lds_region + (h * 128 + i * 64 + wu8) * 64;
    __builtin_amdgcn_global_load_lds((gas_ptr)g, (las_ptr)d, 16, 0, 0);
  }
}

__device__ __forceinline__ void bar() {
  asm volatile("" ::: "memory");
  __builtin_amdgcn_s_barrier();
  asm volatile("" ::: "memory");
}
__device__ __forceinline__ void mfma_open() {
  bar();
  asm volatile("s_waitcnt lgkmcnt(0)" ::: "memory");
  __builtin_amdgcn_sched_barrier(0);  // rule #18: keep MFMAs below the lgkmcnt
  __builtin_amdgcn_s_setprio(1);
}
__device__ __forceinline__ void mfma_close() {
  __builtin_amdgcn_s_setprio(0);
  bar();
}
__device__ __forceinline__ void mfma_close_w4() {
  __builtin_amdgcn_s_setprio(0);
  asm volatile("s_waitcnt vmcnt(4)" ::: "memory");  // counted: never 0 in main loop (T4)
  bar();
}
__device__ __forceinline__ void mfma_close_w0() {
  __builtin_amdgcn_s_setprio(0);
  asm volatile("s_waitcnt vmcnt(0)" ::: "memory");
  bar();
}

struct GemmCtx {
  const f16 *a0k0, *a0k1, *a1k0, *a1k1, *b0k0, *b0k1, *b1k0, *b1k1;
  f16 *bufA0, *bufA1, *bufB0, *bufB1;
  int wl8, wu8, cs;
};

// 15 steady-state double-K-tile iterations (tiles 0..29 of a 32-tile pass)
__device__ __forceinline__ void loop15(const GemmCtx& c, const f16* Ab, const f16* Bb,
                                       f32x4 (&acc)[8][4]) {
  f16x8 fa[4][2], fb0[2][2], fb1[2][2];
#pragma unroll 1
  for (int it = 0; it < 15; ++it) {
    const int Ta = 2 * it + 1, Tb = 2 * it + 2, Tc = 2 * it + 3;
    // ---- K-tile 2*it (buf0): 4 phases ----
    lda4(fa, c.a0k0, c.a0k1, 0);
    ldb2(fb0, c.b0k0, c.b0k1, 0);
    stage_half(Ab, c.bufA1, Ta, 0, c.wl8, c.wu8, c.cs);
    mfma_open(); quad_mfma<0, 0>(acc, fa, fb0); mfma_close();

    ldb2(fb1, c.b0k0, c.b0k1, 1);
    stage_half(Ab, c.bufA1, Ta, 1, c.wl8, c.wu8, c.cs);
    mfma_open(); quad_mfma<0, 2>(acc, fa, fb1); mfma_close();

    lda4(fa, c.a0k0, c.a0k1, 1);
    stage_half(Bb, c.bufB0, Tb, 0, c.wl8, c.wu8, c.cs);
    mfma_open(); quad_mfma<4, 2>(acc, fa, fb1); mfma_close();

    stage_half(Bb, c.bufB0, Tb, 1, c.wl8, c.wu8, c.cs);
    mfma_open(); quad_mfma<4, 0>(acc, fa, fb0); mfma_close_w4();  // tile Ta resident

    // ---- K-tile 2*it+1 (buf1): 4 phases ----
    lda4(fa, c.a1k0, c.a1k1, 0);
    ldb2(fb0, c.b1k0, c.b1k1, 0);
    stage_half(Ab, c.bufA0, Tb, 0, c.wl8, c.wu8, c.cs);
    mfma_open(); quad_mfma<0, 0>(acc, fa, fb0); mfma_close();

    ldb2(fb1, c.b1k0, c.b1k1, 1);
    stage_half(Ab, c.bufA0, Tb, 1, c.wl8, c.wu8, c.cs);
    mfma_open(); quad_mfma<0, 2>(acc, fa, fb1); mfma_close();

    lda4(fa, c.a1k0, c.a1k1, 1);
    stage_half(Bb, c.bufB1, Tc, 0, c.wl8, c.wu8, c.cs);
    mfma_open(); quad_mfma<4, 2>(acc, fa, fb1); mfma_close();

    stage_half(Bb, c.bufB1, Tc, 1, c.wl8, c.wu8, c.cs);
    mfma_open(); quad_mfma<4, 0>(acc, fa, fb0); mfma_close_w4();  // tile Tb resident
  }
}

__device__ __forceinline__ void epilogue(f32x4 (&acc)[8][4], const float* __restrict__ b1,
                                         const float* __restrict__ w2s,
                                         float* __restrict__ zacc, int e, int c0, int h0,
                                         int wm, int wn, int quad, int l15) {
  float b1v[4], wsv[4];
#pragma unroll
  for (int nf = 0; nf < 4; ++nf) {
    int h = h0 + wn * 64 + nf * 16 + l15;
    b1v[nf] = b1[e * HDIM + h];
    wsv[nf] = w2s[e * HDIM + h];
  }
#pragma unroll
  for (int mf = 0; mf < 8; ++mf) {
    float pr[4];
#pragma unroll
    for (int rr = 0; rr < 4; ++rr) {
      float t = 0.f;
#pragma unroll
      for (int nf = 0; nf < 4; ++nf) {
        float v = acc[mf][nf][rr] + b1v[nf];
        t += (v > 0.f ? v : 0.f) * wsv[nf];
      }
      pr[rr] = t;
    }
#pragma unroll
    for (int rr = 0; rr < 4; ++rr)
#pragma unroll
      for (int off = 1; off < 16; off <<= 1) pr[rr] += __shfl_xor(pr[rr], off, 64);
    if (l15 == 0) {
      int m = c0 + wm * 128 + mf * 16 + quad * 4;
#pragma unroll
      for (int rr = 0; rr < 4; ++rr) atomicAdd(&zacc[e * CAP + m + rr], pr[rr]);
    }
  }
}

__global__ __launch_bounds__(512, 2) void gemm_kernel(const f16* __restrict__ A16,
                                                      const f16* __restrict__ W1T,
                                                      const float* __restrict__ b1,
                                                      const float* __restrict__ w2s,
                                                      float* __restrict__ zacc) {
  __shared__ __align__(16) f16 lds[4 * 256 * 64];  // 128 KiB
  const int tid = threadIdx.x;
  const int wid = tid >> 6, lane = tid & 63;
  const int wm = wid >> 2, wn = wid & 3;      // 2(M) x 4(N) wave grid, wave owns 128x64
  const int quad = lane >> 4, l15 = lane & 15;
  const int l3 = lane >> 3, c7 = lane & 7;
  const int cs = c7 ^ l3;                     // pre-swizzled source chunk
  const int wl8 = wid * 8 + l3, wu8 = wid * 8;

  int bid = blockIdx.x;
  int e = bid & 7;                            // one expert per XCD (round-robin dispatch)
  int idx = bid >> 3;                         // 0..31 within expert
  int cT = idx >> 2, hTp = idx & 3;
  int c0 = cT * 256;
  int h0a = hTp * 256, h0b = (hTp + 4) * 256;

  const f16* Abase = A16 + ((size_t)e * CAP + c0) * DDIM;
  const f16* Bbase0 = W1T + ((size_t)e * HDIM + h0a) * DDIM;
  const f16* Bbase1 = W1T + ((size_t)e * HDIM + h0b) * DDIM;

  GemmCtx c;
  c.bufA0 = &lds[0];
  c.bufB0 = &lds[16384];
  c.bufA1 = &lds[2 * 16384];
  c.bufB1 = &lds[3 * 16384];
  c.wl8 = wl8; c.wu8 = wu8; c.cs = cs;

  const int so0 = (quad ^ c7) * 8;            // swizzled slot, k-frag 0
  const int so1 = ((quad + 4) ^ c7) * 8;      // swizzled slot, k-frag 1
  c.a0k0 = c.bufA0 + (wm * 128 + l15) * 64 + so0;
  c.a0k1 = c.bufA0 + (wm * 128 + l15) * 64 + so1;
  c.a1k0 = c.a0k0 + 2 * 16384;
  c.a1k1 = c.a0k1 + 2 * 16384;
  c.b0k0 = c.bufB0 + (wn * 64 + l15) * 64 + so0;
  c.b0k1 = c.bufB0 + (wn * 64 + l15) * 64 + so1;
  c.b1k0 = c.b0k0 + 2 * 16384;
  c.b1k1 = c.b0k1 + 2 * 16384;

  f32x4 acc[8][4];
#pragma unroll
  for (int i = 0; i < 8; ++i)
#pragma unroll
    for (int jj = 0; jj < 4; ++jj) acc[i][jj] = (f32x4){0.f, 0.f, 0.f, 0.f};

  // prologue: half-0 tile0 A+B -> buf0 (8 loads), tile1 B -> buf1 (4 loads); wait oldest 8
  stage_half(Abase, c.bufA0, 0, 0, wl8, wu8, cs);
  stage_half(Abase, c.bufA0, 0, 1, wl8, wu8, cs);
  stage_half(Bbase0, c.bufB0, 0, 0, wl8, wu8, cs);
  stage_half(Bbase0, c.bufB0, 0, 1, wl8, wu8, cs);
  stage_half(Bbase0, c.bufB1, 1, 0, wl8, wu8, cs);
  stage_half(Bbase0, c.bufB1, 1, 1, wl8, wu8, cs);
  asm volatile("s_waitcnt vmcnt(4)" ::: "memory");
  bar();

  // ================= half 0: output tile (c0, h0a) =================
  loop15(c, Abase, Bbase0, acc);

  // cross-boundary it=15: compute tiles 30,31; stage half-1 K-tiles 0,1 (pipeline stays warm)
  {
    f16x8 fa[4][2], fb0[2][2], fb1[2][2];
    lda4(fa, c.a0k0, c.a0k1, 0);
    ldb2(fb0, c.b0k0, c.b0k1, 0);
    stage_half(Abase, c.bufA1, 31, 0, wl8, wu8, cs);
    mfma_open(); quad_mfma<0, 0>(acc, fa, fb0); mfma_close();

    ldb2(fb1, c.b0k0, c.b0k1, 1);
    stage_half(Abase, c.bufA1, 31, 1, wl8, wu8, cs);
    mfma_open(); quad_mfma<0, 2>(acc, fa, fb1); mfma_close();

    lda4(fa, c.a0k0, c.a0k1, 1);
    stage_half(Bbase1, c.bufB0, 0, 0, wl8, wu8, cs);   // half-1 K-tile 0 B
    mfma_open(); quad_mfma<4, 2>(acc, fa, fb1); mfma_close();

    stage_half(Bbase1, c.bufB0, 0, 1, wl8, wu8, cs);
    mfma_open(); quad_mfma<4, 0>(acc, fa, fb0); mfma_close_w4();  // tile 31 A resident

    lda4(fa, c.a1k0, c.a1k1, 0);
    ldb2(fb0, c.b1k0, c.b1k1, 0);
    stage_half(Abase, c.bufA0, 0, 0, wl8, wu8, cs);    // half-1 K-tile 0 A (k=0 again)
    mfma_open(); quad_mfma<0, 0>(acc, fa, fb0); mfma_close();

    ldb2(fb1, c.b1k0, c.b1k1, 1);
    stage_half(Abase, c.bufA0, 0, 1, wl8, wu8, cs);
    mfma_open(); quad_mfma<0, 2>(acc, fa, fb1); mfma_close();

    lda4(fa, c.a1k0, c.a1k1, 1);
    stage_half(Bbase1, c.bufB1, 1, 0, wl8, wu8, cs);   // half-1 K-tile 1 B
    mfma_open(); quad_mfma<4, 2>(acc, fa, fb1); mfma_close();

    stage_half(Bbase1, c.bufB1, 1, 1, wl8, wu8, cs);
    mfma_open(); quad_mfma<4, 0>(acc, fa, fb0); mfma_close_w4();  // half-1 tile 0 resident
  }

  // epilogue half 0 (runs inside warm pipeline; its vmem ops are absorbed by next vmcnt(4))
  epilogue(acc, b1, w2s, zacc, e, c0, h0a, wm, wn, quad, l15);
#pragma unroll
  for (int i = 0; i < 8; ++i)
#pragma unroll
    for (int jj = 0; jj < 4; ++jj) acc[i][jj] = (f32x4){0.f, 0.f, 0.f, 0.f};

  // ================= half 1: output tile (c0, h0b) =================
  loop15(c, Abase, Bbase1, acc);

  // peeled final iteration: tiles 30 (buf0), 31 (buf1); only tile31.A left to stage
  {
    f16x8 fa[4][2], fb0[2][2], fb1[2][2];
    lda4(fa, c.a0k0, c.a0k1, 0);
    ldb2(fb0, c.b0k0, c.b0k1, 0);
    stage_half(Abase, c.bufA1, 31, 0, wl8, wu8, cs);
    mfma_open(); quad_mfma<0, 0>(acc, fa, fb0); mfma_close();

    ldb2(fb1, c.b0k0, c.b0k1, 1);
    stage_half(Abase, c.bufA1, 31, 1, wl8, wu8, cs);
    mfma_open(); quad_mfma<0, 2>(acc, fa, fb1); mfma_close();

    lda4(fa, c.a0k0, c.a0k1, 1);
    mfma_open(); quad_mfma<4, 2>(acc, fa, fb1); mfma_close();

    mfma_open(); quad_mfma<4, 0>(acc, fa, fb0); mfma_close_w0();  // drain: tile31 resident

    lda4(fa, c.a1k0, c.a1k1, 0);
    ldb2(fb0, c.b1k0, c.b1k1, 0);
    mfma_open(); quad_mfma<0, 0>(acc, fa, fb0); mfma_close();

    ldb2(fb1, c.b1k0, c.b1k1, 1);
    mfma_open(); quad_mfma<0, 2>(acc, fa, fb1); mfma_close();

    lda4(fa, c.a1k0, c.a1k1, 1);
    mfma_open(); quad_mfma<4, 2>(acc, fa, fb1); mfma_close();

    mfma_open(); quad_mfma<4, 0>(acc, fa, fb0);
    __builtin_amdgcn_s_setprio(0);
  }

  epilogue(acc, b1, w2s, zacc, e, c0, h0b, wm, wn, quad, l15);
}

// ---------------- fused combine + per-batch-row log_softmax (1024 thr: more gather TLP) ----------------
__global__ __launch_bounds__(1024) void tail_kernel(const int* __restrict__ eid,
                                                    const int* __restrict__ locb,
                                                    const float* __restrict__ wts,
                                                    const float* __restrict__ zacc,
                                                    const float* __restrict__ b2s,
                                                    float* __restrict__ out) {
  __shared__ float red[16];
  int b = blockIdx.x, tid = threadIdx.x;
  int wid = tid >> 6, lane = tid & 63;
  float v[2];
  float mx = -1e30f;
#pragma unroll
  for (int i = 0; i < 2; ++i) {
    int s = b * TT + i * 1024 + tid;
    float zz = 0.f;
#pragma unroll
    for (int k = 0; k < 2; ++k) {
      int e = eid[2 * s + k], loc = locb[2 * s + k];
      if (loc < CAP) zz += wts[2 * s + k] * (zacc[e * CAP + loc] + b2s[e]);
    }
    v[i] = zz;
    mx = fmaxf(mx, zz);
  }
  for (int off = 32; off > 0; off >>= 1) mx = fmaxf(mx, __shfl_xor(mx, off, 64));
  if (lane == 0) red[wid] = mx;
  __syncthreads();
  mx = red[0];
#pragma unroll
  for (int j = 1; j < 16; ++j) mx = fmaxf(mx, red[j]);
  float sum = expf(v[0] - mx) + expf(v[1] - mx);
  for (int off = 32; off > 0; off >>= 1) sum += __shfl_xor(sum, off, 64);
  __syncthreads();
  if (lane == 0) red[wid] = sum;
  __syncthreads();
  sum = 0.f;
#pragma unroll
  for (int j = 0; j < 16; ++j) sum += red[j];
  float lse = mx + logf(sum);
#pragma unroll
  for (int i = 0; i < 2; ++i) out[b * TT + i * 1024 + tid] = v[i] - lse;
}

extern "C" void kernel_launch(void* const* d_in, const int* in_sizes, int n_in,
                              void* d_out, int out_size, void* d_ws, size_t ws_size,
                              hipStream_t stream) {
  const float* x  = (const float*)d_in[0];
  const float* wg = (const float*)d_in[1];
  const float* w1 = (const float*)d_in[2];
  const float* b1 = (const float*)d_in[3];
  const float* w2 = (const float*)d_in[4];
  const float* b2 = (const float*)d_in[5];
  float* out = (float*)d_out;

  char* ws = (char*)d_ws;
  size_t off = 0;
  auto alloc = [&](size_t bytes) -> char* {
    char* p = ws + off;
    off += (bytes + 255) & ~(size_t)255;
    return p;
  };
  f16* A16 = (f16*)alloc((size_t)NE * CAP * DDIM * 2);
  f16* W1T = (f16*)alloc((size_t)NE * HDIM * DDIM * 2);
  float* w2s = (float*)alloc((size_t)NE * HDIM * 4);
  float* b2s = (float*)alloc(NE * 4);
  int* eid = (int*)alloc((size_t)S_TOK * 2 * 4);
  float* wts = (float*)alloc((size_t)S_TOK * 2 * 4);
  int* locb = (int*)alloc((size_t)S_TOK * 2 * 4);
  int* slot_token = (int*)alloc((size_t)NE * CAP * 4);
  float* zacc = (float*)alloc((size_t)NE * CAP * 4);
  if (off > ws_size) return;  // workspace too small: fail loudly via wrong output

  prep_kernel<<<K1_GRID, 256, 0, stream>>>(w1, w2, b2, x, wg, eid, wts, slot_token, zacc,
                                           W1T, w2s, b2s);
  scan_kernel<<<1, 1024, 0, stream>>>(eid, locb, slot_token);
  abuild_kernel<<<NE * CAP / 4, 256, 0, stream>>>(x, slot_token, A16);
  gemm_kernel<<<NE * 32, 512, 0, stream>>>(A16, W1T, b1, w2s, zacc);
  tail_kernel<<<NBATCH, 1024, 0, stream>>>(eid, locb, wts, zacc, b2s, out);
}